// Round 1
// baseline (7181.190 us; speedup 1.0000x reference)
//
#include <hip/hip_runtime.h>

#define H 22
#define SLOPE 0.01f
#define EPS 1e-5f
#define NBLK 1024
#define NTHR 256

__device__ __forceinline__ float leaky(float u) { return u > 0.f ? u : SLOPE * u; }

// block-level stats reduction: per-thread sum/sq[H] -> atomicAdd into accOut[0..2H)
__device__ __forceinline__ void block_reduce_stats(float* sum, float* sq, float* accOut) {
    __shared__ float red[4][2 * H];
    int lane = threadIdx.x & 63;
    int w = threadIdx.x >> 6;
#pragma unroll
    for (int j = 0; j < H; j++) {
        float s = sum[j], q = sq[j];
#pragma unroll
        for (int o = 32; o > 0; o >>= 1) {
            s += __shfl_xor(s, o, 64);
            q += __shfl_xor(q, o, 64);
        }
        if (lane == 0) { red[w][j] = s; red[w][H + j] = q; }
    }
    __syncthreads();
    if (threadIdx.x < 2 * H) {
        float v = red[0][threadIdx.x] + red[1][threadIdx.x] +
                  red[2][threadIdx.x] + red[3][threadIdx.x];
        atomicAdd(&accOut[threadIdx.x], v);
    }
}

// input projection: z0 = Wp @ x_row + bp, feature-major store, accumulate stats
__global__ void __launch_bounds__(NTHR) proj_kernel(
    const float* __restrict__ x, const float* __restrict__ Wp,
    const float* __restrict__ bp, float* __restrict__ bufZ,
    float* __restrict__ accOut, int N) {
    __shared__ float4 sW4[H * 16];
    __shared__ float sb[H];
    int t = threadIdx.x;
    for (int idx = t; idx < H * 16; idx += NTHR) sW4[idx] = ((const float4*)Wp)[idx];
    if (t < H) sb[t] = bp[t];
    __syncthreads();

    float sum[H], sq[H];
#pragma unroll
    for (int j = 0; j < H; j++) { sum[j] = 0.f; sq[j] = 0.f; }

    int gid = blockIdx.x * NTHR + t;
    int gstride = gridDim.x * NTHR;
    for (int i = gid; i < N; i += gstride) {
        float4 xr[16];
        const float4* xp = (const float4*)x + (size_t)i * 16;
#pragma unroll
        for (int q = 0; q < 16; q++) xr[q] = xp[q];
#pragma unroll
        for (int j = 0; j < H; j++) {
            float acc = sb[j];
#pragma unroll
            for (int q = 0; q < 16; q++) {
                float4 wv = sW4[j * 16 + q];
                acc += wv.x * xr[q].x + wv.y * xr[q].y + wv.z * xr[q].z + wv.w * xr[q].w;
            }
            bufZ[(size_t)j * N + i] = acc;
            sum[j] += acc;
            sq[j] += acc * acc;
        }
    }
    block_reduce_stats(sum, sq, accOut);
}

// pass A: h' = (first ? bn(z) : leaky(h + bn(z))) ; zA = W1 @ h' + b1 ; stats(zA)
template <int FIRST>
__global__ void __launch_bounds__(NTHR) pass_a(
    float* __restrict__ bufH, float* __restrict__ bufZ,
    const float* __restrict__ accIn, float* __restrict__ accOut,
    const float* __restrict__ g, const float* __restrict__ be,
    const float* __restrict__ W, const float* __restrict__ b, int N) {
    __shared__ float sW[H * H];
    __shared__ float sa[H], sc[H], sb[H];
    int t = threadIdx.x;
    for (int idx = t; idx < H * H; idx += NTHR) sW[idx] = W[idx];
    if (t < H) {
        float invN = 1.0f / (float)N;
        float mu = accIn[t] * invN;
        float var = accIn[H + t] * invN - mu * mu;
        float aj = g[t] * rsqrtf(var + EPS);
        sa[t] = aj;
        sc[t] = be[t] - aj * mu;
        sb[t] = b[t];
    }
    __syncthreads();

    float sum[H], sq[H];
#pragma unroll
    for (int j = 0; j < H; j++) { sum[j] = 0.f; sq[j] = 0.f; }

    int gid = blockIdx.x * NTHR + t;
    int gstride = gridDim.x * NTHR;
    for (int i0 = gid; i0 < N; i0 += 2 * gstride) {
        int i1 = i0 + gstride;
        bool two = (i1 < N);
        float h0[H], h1[H];
#pragma unroll
        for (int j = 0; j < H; j++) {
            size_t off = (size_t)j * N + i0;
            float z = bufZ[off];
            float u = sa[j] * z + sc[j];
            if (!FIRST) u = leaky(bufH[off] + u);
            h0[j] = u;
            bufH[off] = u;
        }
        if (two) {
#pragma unroll
            for (int j = 0; j < H; j++) {
                size_t off = (size_t)j * N + i1;
                float z = bufZ[off];
                float u = sa[j] * z + sc[j];
                if (!FIRST) u = leaky(bufH[off] + u);
                h1[j] = u;
                bufH[off] = u;
            }
        } else {
#pragma unroll
            for (int j = 0; j < H; j++) h1[j] = 0.f;
        }
#pragma unroll
        for (int j = 0; j < H; j++) {
            float a0 = sb[j], a1 = sb[j];
#pragma unroll
            for (int m = 0; m < H; m++) {
                float wv = sW[j * H + m];
                a0 += wv * h0[m];
                a1 += wv * h1[m];
            }
            bufZ[(size_t)j * N + i0] = a0;
            sum[j] += a0;
            sq[j] += a0 * a0;
            if (two) {
                bufZ[(size_t)j * N + i1] = a1;
                sum[j] += a1;
                sq[j] += a1 * a1;
            }
        }
    }
    block_reduce_stats(sum, sq, accOut);
}

// pass B: t = leaky(bn(zA)) ; zB = W2 @ t + b2 (in place) ; stats(zB)
__global__ void __launch_bounds__(NTHR) pass_b(
    float* __restrict__ bufZ,
    const float* __restrict__ accIn, float* __restrict__ accOut,
    const float* __restrict__ g, const float* __restrict__ be,
    const float* __restrict__ W, const float* __restrict__ b, int N) {
    __shared__ float sW[H * H];
    __shared__ float sa[H], sc[H], sb[H];
    int t = threadIdx.x;
    for (int idx = t; idx < H * H; idx += NTHR) sW[idx] = W[idx];
    if (t < H) {
        float invN = 1.0f / (float)N;
        float mu = accIn[t] * invN;
        float var = accIn[H + t] * invN - mu * mu;
        float aj = g[t] * rsqrtf(var + EPS);
        sa[t] = aj;
        sc[t] = be[t] - aj * mu;
        sb[t] = b[t];
    }
    __syncthreads();

    float sum[H], sq[H];
#pragma unroll
    for (int j = 0; j < H; j++) { sum[j] = 0.f; sq[j] = 0.f; }

    int gid = blockIdx.x * NTHR + t;
    int gstride = gridDim.x * NTHR;
    for (int i0 = gid; i0 < N; i0 += 2 * gstride) {
        int i1 = i0 + gstride;
        bool two = (i1 < N);
        float t0[H], t1[H];
#pragma unroll
        for (int j = 0; j < H; j++) {
            float z = bufZ[(size_t)j * N + i0];
            t0[j] = leaky(sa[j] * z + sc[j]);
        }
        if (two) {
#pragma unroll
            for (int j = 0; j < H; j++) {
                float z = bufZ[(size_t)j * N + i1];
                t1[j] = leaky(sa[j] * z + sc[j]);
            }
        } else {
#pragma unroll
            for (int j = 0; j < H; j++) t1[j] = 0.f;
        }
#pragma unroll
        for (int j = 0; j < H; j++) {
            float a0 = sb[j], a1 = sb[j];
#pragma unroll
            for (int m = 0; m < H; m++) {
                float wv = sW[j * H + m];
                a0 += wv * t0[m];
                a1 += wv * t1[m];
            }
            bufZ[(size_t)j * N + i0] = a0;
            sum[j] += a0;
            sq[j] += a0 * a0;
            if (two) {
                bufZ[(size_t)j * N + i1] = a1;
                sum[j] += a1;
                sq[j] += a1 * a1;
            }
        }
    }
    block_reduce_stats(sum, sq, accOut);
}

// final: h16 = leaky(h15 + bn(zB15)) ; out = Wo @ h16 + bo
__global__ void __launch_bounds__(NTHR) final_kernel(
    const float* __restrict__ bufH, const float* __restrict__ bufZ,
    const float* __restrict__ accIn,
    const float* __restrict__ g, const float* __restrict__ be,
    const float* __restrict__ Wo, const float* __restrict__ bo,
    float* __restrict__ out, int N) {
    __shared__ float sa[H], sc[H], sWo[H];
    __shared__ float sbo;
    int t = threadIdx.x;
    if (t < H) {
        float invN = 1.0f / (float)N;
        float mu = accIn[t] * invN;
        float var = accIn[H + t] * invN - mu * mu;
        float aj = g[t] * rsqrtf(var + EPS);
        sa[t] = aj;
        sc[t] = be[t] - aj * mu;
        sWo[t] = Wo[t];
    }
    if (t == 0) sbo = bo[0];
    __syncthreads();

    int gid = blockIdx.x * NTHR + t;
    int gstride = gridDim.x * NTHR;
    for (int i = gid; i < N; i += gstride) {
        float acc = sbo;
#pragma unroll
        for (int j = 0; j < H; j++) {
            size_t off = (size_t)j * N + i;
            float u = leaky(bufH[off] + sa[j] * bufZ[off] + sc[j]);
            acc += sWo[j] * u;
        }
        out[i] = acc;
    }
}

extern "C" void kernel_launch(void* const* d_in, const int* in_sizes, int n_in,
                              void* d_out, int out_size, void* d_ws, size_t ws_size,
                              hipStream_t stream) {
    const float* x    = (const float*)d_in[0];
    const float* Wp   = (const float*)d_in[1];
    const float* bp   = (const float*)d_in[2];
    const float* g0   = (const float*)d_in[3];
    const float* be0  = (const float*)d_in[4];
    const float* W1s  = (const float*)d_in[5];
    const float* b1s  = (const float*)d_in[6];
    const float* g1s  = (const float*)d_in[7];
    const float* be1s = (const float*)d_in[8];
    const float* W2s  = (const float*)d_in[9];
    const float* b2s  = (const float*)d_in[10];
    const float* g2s  = (const float*)d_in[11];
    const float* be2s = (const float*)d_in[12];
    const float* Wo   = (const float*)d_in[13];
    const float* bo   = (const float*)d_in[14];

    int N = in_sizes[0] / 64;

    float* bufH = (float*)d_ws;
    float* bufZ = bufH + (size_t)N * H;
    float* acc  = bufZ + (size_t)N * H;  // 33 slots x 44 floats

    hipMemsetAsync(acc, 0, 33 * 2 * H * sizeof(float), stream);

    dim3 grid(NBLK), block(NTHR);

    // z0 = Wp @ x + bp  -> bufZ, stats -> acc slot 0
    proj_kernel<<<grid, block, 0, stream>>>(x, Wp, bp, bufZ, acc, N);

    // block 0
    pass_a<1><<<grid, block, 0, stream>>>(bufH, bufZ, acc + 0, acc + 2 * H,
                                          g0, be0, W1s, b1s, N);
    pass_b<<<grid, block, 0, stream>>>(bufZ, acc + 2 * H, acc + 4 * H,
                                       g1s, be1s, W2s, b2s, N);

    for (int k = 1; k < 16; k++) {
        pass_a<0><<<grid, block, 0, stream>>>(
            bufH, bufZ, acc + (size_t)2 * H * (2 * k), acc + (size_t)2 * H * (2 * k + 1),
            g2s + (k - 1) * H, be2s + (k - 1) * H, W1s + k * H * H, b1s + k * H, N);
        pass_b<<<grid, block, 0, stream>>>(
            bufZ, acc + (size_t)2 * H * (2 * k + 1), acc + (size_t)2 * H * (2 * k + 2),
            g1s + k * H, be1s + k * H, W2s + k * H * H, b2s + k * H, N);
    }

    final_kernel<<<grid, block, 0, stream>>>(
        bufH, bufZ, acc + (size_t)2 * H * 32, g2s + 15 * H, be2s + 15 * H,
        Wo, bo, (float*)d_out, N);
}